// Round 14
// baseline (34.059 us; speedup 1.0000x reference)
//
#include <hip/hip_runtime.h>
#include <hip/hip_bf16.h>

// Problem constants: features [16, 512, 56, 56] f32, k=3 -> d=1
#define BB 16
#define CC 512
#define HH 56
#define WW 56
#define HW (HH * WW)
#define NPIX (BB * HW)   // 50176 output pixels
#define CGROUPS 8

typedef float v4f __attribute__((ext_vector_type(4)));

// DPP lane shifts within each 16-lane row (= our sc channel group), R13-proven:
//   "value from lane-1" = row_shr:1 (ctrl 0x111)
//   "value from lane+1" = row_shl:1 (ctrl 0x101)
// Invalid edge lanes keep own value; q==0 / q>=13 clamp fixups overwrite them.
__device__ __forceinline__ float dpp_prev(float x) {  // dest[i] = src[i-1]
    return __int_as_float(__builtin_amdgcn_update_dpp(
        __float_as_int(x), __float_as_int(x), 0x111, 0xf, 0xf, false));
}
__device__ __forceinline__ float dpp_next(float x) {  // dest[i] = src[i+1]
    return __int_as_float(__builtin_amdgcn_update_dpp(
        __float_as_int(x), __float_as_int(x), 0x101, 0xf, 0xf, false));
}

// Proven math (R1..R13, absmax 0 at f32); masks & 1/9 cancel in cosine:
//   V  = mym*g(y-1) + g(y) + myp*g(y+1)
//   w3 = mym*g(y)   + g(cl(y+1)) + myp*g(cl(y+2))
//   w4 = mym*g(cl(y-2)) + g(cl(y-1)) + myp*g(y)
//   f1 = mxm*V(cl(x-2)) + V(cl(x-1)) + mxp*V(x)
//   f2 = mxm*V(x) + V(cl(x+1)) + mxp*V(cl(x+2))
//   f3 = mxm*w3(cl(x-1)) + w3(x) + mxp*w3(cl(x+1))
//   f4 = mxm*w4(cl(x-1)) + w4(x) + mxp*w4(cl(x+1))
// Wave = one row y. lane = sc*16 + q: sc = channel sub-group (4 ch/iter),
// q = x-quad (float4/thread, q<14 active).
// R14: ALL strips (boundary included) use the counted-vmcnt pipeline via 5
// per-row running pointers (clamped offsets) — R13 left 2/14 strips on the
// slow compiler-scheduled path, which set the max-over-blocks critical path.
template <int NITER, bool WRITE_OUT>
__global__ __launch_bounds__(256, 4) void ComputeTotalSim_84267258347855_kernel(
    const float* __restrict__ feat, float* __restrict__ ws, float* __restrict__ out) {
    const int wave = threadIdx.x >> 6;
    const int lane = threadIdx.x & 63;
    const int sc = lane >> 4;
    const int q = lane & 15;
    const int qs = (q <= 13) ? q : 13;  // idle lanes load safe real data
    const int x0 = 4 * qs;
    const int b = blockIdx.z;
    const int cg = blockIdx.x;
    const int y = blockIdx.y * 4 + wave;

    const float mym = (y >= 1) ? 1.f : 0.f;
    const float myp = (y <= HH - 2) ? 1.f : 0.f;
    const float mxm0 = (q == 0) ? 0.f : 1.f;   // applies only at j=0
    const float mxp3 = (q >= 13) ? 0.f : 1.f;  // applies only at j=3

    const int ry0 = (y - 2 < 0) ? 0 : y - 2;
    const int ry1 = (y - 1 < 0) ? 0 : y - 1;
    const int ry3 = (y + 1 > HH - 1) ? HH - 1 : y + 1;
    const int ry4 = (y + 2 > HH - 1) ? HH - 1 : y + 2;

    // channels: cg*(4*NITER) + 4*k + sc, k = 0..NITER-1
    const float* p = feat + ((size_t)b * CC + (size_t)cg * (4 * NITER) + sc) * HW;
    // 5 per-row running pointers (clamped). Advanced by 4*HW per iteration.
    const float* p0 = p + (ry0 * WW + x0);
    const float* p1 = p + (ry1 * WW + x0);
    const float* p2 = p + (y   * WW + x0);
    const float* p3 = p + (ry3 * WW + x0);
    const float* p4 = p + (ry4 * WW + x0);

    // 24 named accumulators (NO arrays anywhere -> no scratch possible)
    float sA0 = 0, sA1 = 0, sA2 = 0, sA3 = 0;  // s12h
    float sB0 = 0, sB1 = 0, sB2 = 0, sB3 = 0;  // s11
    float sC0 = 0, sC1 = 0, sC2 = 0, sC3 = 0;  // s22
    float sD0 = 0, sD1 = 0, sD2 = 0, sD3 = 0;  // s12v
    float sE0 = 0, sE1 = 0, sE2 = 0, sE3 = 0;  // s33
    float sF0 = 0, sF1 = 0, sF2 = 0, sF3 = 0;  // s44

#define STEP(A0_, A1_, A2_, A3_, A4_)                                           \
    {                                                                           \
        const float Vx = fmaf(mym, A1_.x, fmaf(myp, A3_.x, A2_.x));             \
        const float Vy = fmaf(mym, A1_.y, fmaf(myp, A3_.y, A2_.y));             \
        const float Vz = fmaf(mym, A1_.z, fmaf(myp, A3_.z, A2_.z));             \
        const float Vw = fmaf(mym, A1_.w, fmaf(myp, A3_.w, A2_.w));             \
        const float t3x = fmaf(mym, A2_.x, fmaf(myp, A4_.x, A3_.x));            \
        const float t3y = fmaf(mym, A2_.y, fmaf(myp, A4_.y, A3_.y));            \
        const float t3z = fmaf(mym, A2_.z, fmaf(myp, A4_.z, A3_.z));            \
        const float t3w = fmaf(mym, A2_.w, fmaf(myp, A4_.w, A3_.w));            \
        const float t4x = fmaf(mym, A0_.x, fmaf(myp, A2_.x, A1_.x));            \
        const float t4y = fmaf(mym, A0_.y, fmaf(myp, A2_.y, A1_.y));            \
        const float t4z = fmaf(mym, A0_.z, fmaf(myp, A2_.z, A1_.z));            \
        const float t4w = fmaf(mym, A0_.w, fmaf(myp, A2_.w, A1_.w));            \
        float Vm2 = dpp_prev(Vz), Vm1 = dpp_prev(Vw);                           \
        float Vp4 = dpp_next(Vx), Vp5 = dpp_next(Vy);                           \
        float w3m = dpp_prev(t3w), w3p = dpp_next(t3x);                         \
        float w4m = dpp_prev(t4w), w4p = dpp_next(t4x);                         \
        if (q == 0) { Vm2 = Vx; Vm1 = Vx; w3m = t3x; w4m = t4x; }               \
        if (q >= 13) { Vp4 = Vw; Vp5 = Vw; w3p = t3w; w4p = t4w; }              \
        const float f10 = fmaf(mxm0, Vm2, Vm1 + Vx);                            \
        const float f11 = Vm1 + Vx + Vy;                                        \
        const float f12 = Vx + Vy + Vz;                                         \
        const float f13 = fmaf(mxp3, Vw, Vy + Vz);                              \
        const float f20 = fmaf(mxm0, Vx, Vy + Vz);                              \
        const float f21 = Vy + Vz + Vw;                                         \
        const float f22 = Vz + Vw + Vp4;                                        \
        const float f23 = fmaf(mxp3, Vp5, Vw + Vp4);                            \
        const float f30 = fmaf(mxm0, w3m, t3x + t3y);                           \
        const float f31 = t3x + t3y + t3z;                                      \
        const float f32 = t3y + t3z + t3w;                                      \
        const float f33 = fmaf(mxp3, w3p, t3z + t3w);                           \
        const float f40 = fmaf(mxm0, w4m, t4x + t4y);                           \
        const float f41 = t4x + t4y + t4z;                                      \
        const float f42 = t4y + t4z + t4w;                                      \
        const float f43 = fmaf(mxp3, w4p, t4z + t4w);                           \
        sA0 = fmaf(f10, f20, sA0); sA1 = fmaf(f11, f21, sA1);                   \
        sA2 = fmaf(f12, f22, sA2); sA3 = fmaf(f13, f23, sA3);                   \
        sB0 = fmaf(f10, f10, sB0); sB1 = fmaf(f11, f11, sB1);                   \
        sB2 = fmaf(f12, f12, sB2); sB3 = fmaf(f13, f13, sB3);                   \
        sC0 = fmaf(f20, f20, sC0); sC1 = fmaf(f21, f21, sC1);                   \
        sC2 = fmaf(f22, f22, sC2); sC3 = fmaf(f23, f23, sC3);                   \
        sD0 = fmaf(f30, f40, sD0); sD1 = fmaf(f31, f41, sD1);                   \
        sD2 = fmaf(f32, f42, sD2); sD3 = fmaf(f33, f43, sD3);                   \
        sE0 = fmaf(f30, f30, sE0); sE1 = fmaf(f31, f31, sE1);                   \
        sE2 = fmaf(f32, f32, sE2); sE3 = fmaf(f33, f33, sE3);                   \
        sF0 = fmaf(f40, f40, sF0); sF1 = fmaf(f41, f41, sF1);                   \
        sF2 = fmaf(f42, f42, sF2); sF3 = fmaf(f43, f43, sF3);                   \
    }

// 5 loads from the 5 running row pointers, then advance all (C code; the asm
// volatile statements keep program order among themselves; increments are free
// to schedule anywhere — they don't touch vmcnt).
#define LOAD5P(R0, R1, R2, R3, R4)                                              \
    asm volatile("global_load_dwordx4 %0, %1, off" : "=&v"(R0) : "v"(p0));      \
    asm volatile("global_load_dwordx4 %0, %1, off" : "=&v"(R1) : "v"(p1));      \
    asm volatile("global_load_dwordx4 %0, %1, off" : "=&v"(R2) : "v"(p2));      \
    asm volatile("global_load_dwordx4 %0, %1, off" : "=&v"(R3) : "v"(p3));      \
    asm volatile("global_load_dwordx4 %0, %1, off" : "=&v"(R4) : "v"(p4));      \
    p0 += 4 * HW; p1 += 4 * HW; p2 += 4 * HW; p3 += 4 * HW; p4 += 4 * HW;

#define WAITV(N)                                          \
    asm volatile("s_waitcnt vmcnt(" #N ")" ::: "memory"); \
    __builtin_amdgcn_sched_barrier(0);

    v4f A0, A1, A2, A3, A4, B0, B1, B2, B3, B4;

    // ---- unified counted-vmcnt double-buffer pipeline (all strips) ----
    LOAD5P(A0, A1, A2, A3, A4);
    LOAD5P(B0, B1, B2, B3, B4);
    for (int k = 0; k + 4 <= NITER; k += 2) {
        WAITV(5);                                    // A ready, B in flight
        STEP(A0, A1, A2, A3, A4);
        LOAD5P(A0, A1, A2, A3, A4);
        WAITV(5);                                    // B ready, A' in flight
        STEP(B0, B1, B2, B3, B4);
        LOAD5P(B0, B1, B2, B3, B4);
    }
    WAITV(5);
    STEP(A0, A1, A2, A3, A4);
    WAITV(0);
    STEP(B0, B1, B2, B3, B4);
#undef STEP
#undef LOAD5P
#undef WAITV

    // ---- reduce across the 4 channel sub-groups (lanes q, q+16, q+32, q+48) ----
#define RED2(v) { v += __shfl_xor(v, 16, 64); v += __shfl_xor(v, 32, 64); }
    RED2(sA0) RED2(sA1) RED2(sA2) RED2(sA3)
    RED2(sB0) RED2(sB1) RED2(sB2) RED2(sB3)
    RED2(sC0) RED2(sC1) RED2(sC2) RED2(sC3)
    RED2(sD0) RED2(sD1) RED2(sD2) RED2(sD3)
    RED2(sE0) RED2(sE1) RED2(sE2) RED2(sE3)
    RED2(sF0) RED2(sF1) RED2(sF2) RED2(sF3)
#undef RED2

    if (lane < 14) {  // sc==0, q<14
        const int pix = b * HW + y * WW + 4 * q;
        if (WRITE_OUT) {
            v4f r;
            r.x = (float)(0.5 * ((double)sA0 / sqrt((double)sB0 * (double)sC0) +
                                 (double)sD0 / sqrt((double)sE0 * (double)sF0)));
            r.y = (float)(0.5 * ((double)sA1 / sqrt((double)sB1 * (double)sC1) +
                                 (double)sD1 / sqrt((double)sE1 * (double)sF1)));
            r.z = (float)(0.5 * ((double)sA2 / sqrt((double)sB2 * (double)sC2) +
                                 (double)sD2 / sqrt((double)sE2 * (double)sF2)));
            r.w = (float)(0.5 * ((double)sA3 / sqrt((double)sB3 * (double)sC3) +
                                 (double)sD3 / sqrt((double)sE3 * (double)sF3)));
            *(v4f*)(out + pix) = r;
        } else {
            float* slab = ws + (size_t)cg * 6 * NPIX;
            *(v4f*)(slab + 0 * NPIX + pix) = (v4f){sA0, sA1, sA2, sA3};
            *(v4f*)(slab + 1 * NPIX + pix) = (v4f){sB0, sB1, sB2, sB3};
            *(v4f*)(slab + 2 * NPIX + pix) = (v4f){sC0, sC1, sC2, sC3};
            *(v4f*)(slab + 3 * NPIX + pix) = (v4f){sD0, sD1, sD2, sD3};
            *(v4f*)(slab + 4 * NPIX + pix) = (v4f){sE0, sE1, sE2, sE3};
            *(v4f*)(slab + 5 * NPIX + pix) = (v4f){sF0, sF1, sF2, sF3};
        }
    }
}

// Finalize: 4 px/thread, vectorized v4f loads (12 per thread vs 48 scalar).
__global__ void ComputeTotalSim_finalize(const float* __restrict__ ws,
                                         float* __restrict__ out) {
    const int i = blockIdx.x * blockDim.x + threadIdx.x;  // pixel quad index
    if (i < NPIX / 4) {
        const int px = 4 * i;
        v4f a0 = {0, 0, 0, 0}, a1 = {0, 0, 0, 0}, a2 = {0, 0, 0, 0};
        v4f a3 = {0, 0, 0, 0}, a4 = {0, 0, 0, 0}, a5 = {0, 0, 0, 0};
#pragma unroll
        for (int cg = 0; cg < CGROUPS; ++cg) {
            const float* slab = ws + (size_t)cg * 6 * NPIX;
            a0 += *(const v4f*)(slab + 0 * NPIX + px);
            a1 += *(const v4f*)(slab + 1 * NPIX + px);
            a2 += *(const v4f*)(slab + 2 * NPIX + px);
            a3 += *(const v4f*)(slab + 3 * NPIX + px);
            a4 += *(const v4f*)(slab + 4 * NPIX + px);
            a5 += *(const v4f*)(slab + 5 * NPIX + px);
        }
        v4f r;
        r.x = (float)(0.5 * ((double)a0.x / sqrt((double)a1.x * (double)a2.x) +
                             (double)a3.x / sqrt((double)a4.x * (double)a5.x)));
        r.y = (float)(0.5 * ((double)a0.y / sqrt((double)a1.y * (double)a2.y) +
                             (double)a3.y / sqrt((double)a4.y * (double)a5.y)));
        r.z = (float)(0.5 * ((double)a0.z / sqrt((double)a1.z * (double)a2.z) +
                             (double)a3.z / sqrt((double)a4.z * (double)a5.z)));
        r.w = (float)(0.5 * ((double)a0.w / sqrt((double)a1.w * (double)a2.w) +
                             (double)a3.w / sqrt((double)a4.w * (double)a5.w)));
        *(v4f*)(out + px) = r;
    }
}

extern "C" void kernel_launch(void* const* d_in, const int* in_sizes, int n_in,
                              void* d_out, int out_size, void* d_ws, size_t ws_size,
                              hipStream_t stream) {
    const float* feat = (const float*)d_in[0];
    float* out = (float*)d_out;

    const size_t need = (size_t)CGROUPS * 6 * NPIX * sizeof(float);  // 9.6 MB
    if (ws_size >= need) {
        // Phase 1: per-cgroup slab partials (plain stores, every slot written
        // every call -> no memset needed). Phase 2: sum slabs + cosine.
        dim3 grid(CGROUPS, HH / 4, BB);  // 8 x 14 x 16 = 1792 blocks
        ComputeTotalSim_84267258347855_kernel<CC / (4 * CGROUPS), false>
            <<<grid, 256, 0, stream>>>(feat, (float*)d_ws, out);
        ComputeTotalSim_finalize<<<(NPIX / 4 + 255) / 256, 256, 0, stream>>>(
            (const float*)d_ws, out);
    } else {
        // Fallback: single cgroup covers all 512 channels, writes out directly.
        dim3 grid(1, HH / 4, BB);
        ComputeTotalSim_84267258347855_kernel<CC / 4, true>
            <<<grid, 256, 0, stream>>>(feat, nullptr, out);
    }
}